// Round 5
// baseline (542.191 us; speedup 1.0000x reference)
//
#include <hip/hip_runtime.h>

#define NB 20000
#define EB 320000
#define DIN 128
#define H1D 256
#define H2D 256
#define DOUTD 128
#define SCAN_BLOCKS ((NB + 255) / 256)   // 79
#define NPB 160                          // nodes per agg block (20000 = 125*160)

// ---------------------------------------------------------------------------
// CSR build: histogram -> parallel 3-phase scan -> dinv -> counting-sort
// scatter into int2{src, w_bits} edge records sorted by dst.
// ---------------------------------------------------------------------------

__global__ void zero_kernel(int* __restrict__ p, int n) {
    int t = blockIdx.x * blockDim.x + threadIdx.x;
    if (t < n) p[t] = 0;
}

__global__ void hist_kernel(const int* __restrict__ dst, int* __restrict__ bins) {
    int t = blockIdx.x * blockDim.x + threadIdx.x;
    if (t < EB) atomicAdd(&bins[dst[t]], 1);
}

__global__ __launch_bounds__(256) void scanA_kernel(const int* __restrict__ bins,
                                                    int* __restrict__ loc,
                                                    int* __restrict__ blksum) {
    __shared__ int s[256];
    int t = threadIdx.x;
    int i = blockIdx.x * 256 + t;
    int v = (i < NB) ? bins[i] : 0;
    s[t] = v;
    __syncthreads();
    for (int off = 1; off < 256; off <<= 1) {
        int u = (t >= off) ? s[t - off] : 0;
        __syncthreads();
        s[t] += u;
        __syncthreads();
    }
    if (i < NB) loc[i] = s[t] - v;
    if (t == 255) blksum[blockIdx.x] = s[255];
}

__global__ __launch_bounds__(128) void scanB_kernel(int* __restrict__ blksum) {
    __shared__ int s[128];
    int t = threadIdx.x;
    int v = (t < SCAN_BLOCKS) ? blksum[t] : 0;
    s[t] = v;
    __syncthreads();
    for (int off = 1; off < 128; off <<= 1) {
        int u = (t >= off) ? s[t - off] : 0;
        __syncthreads();
        s[t] += u;
        __syncthreads();
    }
    if (t < SCAN_BLOCKS) blksum[t] = s[t] - v;
}

__global__ __launch_bounds__(256) void scanC_kernel(const int* __restrict__ bins,
                                                    const int* __restrict__ loc,
                                                    const int* __restrict__ blksum,
                                                    int* __restrict__ rs,
                                                    int* __restrict__ cursor,
                                                    float* __restrict__ dinv) {
    int i = blockIdx.x * 256 + threadIdx.x;
    if (i < NB) {
        int r = loc[i] + blksum[blockIdx.x];
        rs[i] = r;
        cursor[i] = r;
        dinv[i] = rsqrtf((float)bins[i] + 1.0f);  // deg = in-degree + 1 (self loop)
    }
    if (i == 0) rs[NB] = EB;
}

__global__ void scatter_kernel(const int* __restrict__ src, const int* __restrict__ dst,
                               const float* __restrict__ dinv,
                               int* __restrict__ cursor, int2* __restrict__ edges) {
    int t = blockIdx.x * blockDim.x + threadIdx.x;
    if (t < EB) {
        int d = dst[t], s = src[t];
        int p = atomicAdd(&cursor[d], 1);
        edges[p] = make_int2(s, __float_as_int(dinv[s] * dinv[d]));
    }
}

// ---------------------------------------------------------------------------
// XCD-sliced aggregation. Feature dim split into 8 slices; slice s is handled
// only by blocks with blockIdx.x%8==s (-> lands on XCD s under round-robin
// dispatch). Per-XCD gather working set = 20000 nodes x slice bytes:
// 5.1 MB (F=256) / 2.5 MB (F=128) -> per-XCD-L2 resident, instead of every
// XCD filling the whole 40 MB feature matrix (the round-4 compulsory floor).
// Edge records are read non-temporally so the 2.5 MB/slice stream does not
// evict the resident slice. Each LPE-lane group owns one node; 2-deep
// unrolled edge loop gives 2 independent gathers in flight per group.
// Buffers are node-interleaved [node*2+b][F]; SPLIT_IN/OUT = batch-split
// [b][node][F] (the X input / final output).
// ---------------------------------------------------------------------------

template <int F, bool SPLIT_IN, bool SPLIT_OUT, bool BIAS, bool PRELU>
__global__ __launch_bounds__(256) void aggs_kernel(
    const float* __restrict__ h, float* __restrict__ out,
    const int* __restrict__ rs, const int2* __restrict__ edges,
    const float* __restrict__ dinv, const float* __restrict__ bias,
    const float* __restrict__ pa) {
    constexpr int SLW = F / 8;        // slice width per batch (floats): 32 / 16
    constexpr int LPB = SLW / 4;      // lanes per batch segment: 8 / 4
    constexpr int LPE = 2 * LPB;      // lanes per node group: 16 / 8
    constexpr int NG = 64 / LPE;      // node groups per wave: 4 / 8
    constexpr int STEP = 4 * NG;      // nodes per block iteration: 16 / 32
    constexpr int ITER = NPB / STEP;  // 10 / 5
    constexpr int GSTRIDE = SPLIT_IN ? F : 2 * F;
    constexpr int OSTRIDE = SPLIT_OUT ? F : 2 * F;

    const int s = blockIdx.x & 7;
    const int chunk = blockIdx.x >> 3;
    const int wid = threadIdx.x >> 6;
    const int lane = threadIdx.x & 63;
    const int g = lane / LPE;
    const int li = lane % LPE;
    const int b = li / LPB;
    const int c = li % LPB;
    const int foff = s * SLW + c * 4;

    const float* gbase = h + (SPLIT_IN ? (size_t)b * NB * F : (size_t)b * F) + foff;
    float* obase = out + (SPLIT_OUT ? (size_t)b * NB * F : (size_t)b * F) + foff;

    const float pav = PRELU ? *pa : 0.0f;
    float4 bv = make_float4(0.f, 0.f, 0.f, 0.f);
    if (BIAS) bv = *(const float4*)(bias + foff);

    int n = chunk * NPB + wid * NG + g;
#pragma unroll 1
    for (int i = 0; i < ITER; ++i, n += STEP) {
        int e0 = rs[n], e1 = rs[n + 1];
        float4 a0 = make_float4(0.f, 0.f, 0.f, 0.f);
        float4 a1 = make_float4(0.f, 0.f, 0.f, 0.f);
        int e = e0;
        for (; e + 2 <= e1; e += 2) {
            long long r0 = __builtin_nontemporal_load((const long long*)(edges + e));
            long long r1 = __builtin_nontemporal_load((const long long*)(edges + e + 1));
            int s0 = (int)r0, s1 = (int)r1;
            float w0 = __int_as_float((int)(r0 >> 32));
            float w1 = __int_as_float((int)(r1 >> 32));
            float4 t0 = *(const float4*)(gbase + (size_t)s0 * GSTRIDE);
            float4 t1 = *(const float4*)(gbase + (size_t)s1 * GSTRIDE);
            a0.x = fmaf(t0.x, w0, a0.x); a0.y = fmaf(t0.y, w0, a0.y);
            a0.z = fmaf(t0.z, w0, a0.z); a0.w = fmaf(t0.w, w0, a0.w);
            a1.x = fmaf(t1.x, w1, a1.x); a1.y = fmaf(t1.y, w1, a1.y);
            a1.z = fmaf(t1.z, w1, a1.z); a1.w = fmaf(t1.w, w1, a1.w);
        }
        if (e < e1) {
            long long r0 = __builtin_nontemporal_load((const long long*)(edges + e));
            int s0 = (int)r0;
            float w0 = __int_as_float((int)(r0 >> 32));
            float4 t0 = *(const float4*)(gbase + (size_t)s0 * GSTRIDE);
            a0.x = fmaf(t0.x, w0, a0.x); a0.y = fmaf(t0.y, w0, a0.y);
            a0.z = fmaf(t0.z, w0, a0.z); a0.w = fmaf(t0.w, w0, a0.w);
        }
        // self loop + combine
        float dv = dinv[n];
        float sw = dv * dv;
        float4 ts = *(const float4*)(gbase + (size_t)n * GSTRIDE);
        float4 r;
        r.x = fmaf(ts.x, sw, a0.x + a1.x);
        r.y = fmaf(ts.y, sw, a0.y + a1.y);
        r.z = fmaf(ts.z, sw, a0.z + a1.z);
        r.w = fmaf(ts.w, sw, a0.w + a1.w);
        if (BIAS) { r.x += bv.x; r.y += bv.y; r.z += bv.z; r.w += bv.w; }
        if (PRELU) {
            r.x = r.x >= 0.f ? r.x : pav * r.x;
            r.y = r.y >= 0.f ? r.y : pav * r.y;
            r.z = r.z >= 0.f ? r.z : pav * r.z;
            r.w = r.w >= 0.f ? r.w : pav * r.w;
        }
        *(float4*)(obase + (size_t)n * OSTRIDE) = r;
    }
}

// ---------------------------------------------------------------------------
// FP32 GEMM: C[M,Nc] = A[M,K] @ W[K,Nc] (+bias) (+prelu).
// 128x64 tile, BK=16, 256 threads, 8x4 microtile. (unchanged from round 4)
// ---------------------------------------------------------------------------
template <bool BIAS, bool PRELU>
__global__ __launch_bounds__(256) void gemm_kernel(const float* __restrict__ A, int M, int K,
                                                   const float* __restrict__ W, int Nc,
                                                   const float* __restrict__ bias,
                                                   const float* __restrict__ pa,
                                                   float* __restrict__ C) {
    __shared__ alignas(16) float As[16][132];
    __shared__ alignas(16) float Bs[16][68];
    int t = threadIdx.x;
    int bm = blockIdx.x * 128;
    int bn = blockIdx.y * 64;
    int tx = t & 15, ty = t >> 4;
    int m0 = ty * 8, n0 = tx * 4;
    int ar = t >> 2, ac4 = (t & 3) * 4;
    int br = t >> 4, bc4 = (t & 15) * 4;

    float acc[8][4] = {};

    for (int k0 = 0; k0 < K; k0 += 16) {
        float4 a0 = make_float4(0.f, 0.f, 0.f, 0.f), a1 = a0;
        int r0 = bm + ar, r1 = bm + ar + 64;
        if (r0 < M) a0 = *(const float4*)&A[(size_t)r0 * K + k0 + ac4];
        if (r1 < M) a1 = *(const float4*)&A[(size_t)r1 * K + k0 + ac4];
        As[ac4 + 0][ar] = a0.x; As[ac4 + 1][ar] = a0.y;
        As[ac4 + 2][ar] = a0.z; As[ac4 + 3][ar] = a0.w;
        As[ac4 + 0][ar + 64] = a1.x; As[ac4 + 1][ar + 64] = a1.y;
        As[ac4 + 2][ar + 64] = a1.z; As[ac4 + 3][ar + 64] = a1.w;
        float4 bv = *(const float4*)&W[(size_t)(k0 + br) * Nc + bn + bc4];
        *(float4*)&Bs[br][bc4] = bv;
        __syncthreads();
#pragma unroll
        for (int k = 0; k < 16; ++k) {
            float4 av0 = *(const float4*)&As[k][m0];
            float4 av1 = *(const float4*)&As[k][m0 + 4];
            float4 bv4 = *(const float4*)&Bs[k][n0];
            float a_[8] = {av0.x, av0.y, av0.z, av0.w, av1.x, av1.y, av1.z, av1.w};
            float b_[4] = {bv4.x, bv4.y, bv4.z, bv4.w};
#pragma unroll
            for (int i = 0; i < 8; ++i)
#pragma unroll
                for (int j = 0; j < 4; ++j)
                    acc[i][j] = fmaf(a_[i], b_[j], acc[i][j]);
        }
        __syncthreads();
    }

    float pav = 0.0f;
    if (PRELU) pav = *pa;
#pragma unroll
    for (int i = 0; i < 8; ++i) {
        int row = bm + m0 + i;
        if (row < M) {
            float v[4];
#pragma unroll
            for (int j = 0; j < 4; ++j) {
                float x = acc[i][j];
                if (BIAS) x += bias[bn + n0 + j];
                if (PRELU) x = (x >= 0.0f) ? x : pav * x;
                v[j] = x;
            }
            *(float4*)&C[(size_t)row * Nc + bn + n0] = make_float4(v[0], v[1], v[2], v[3]);
        }
    }
}

// ---------------------------------------------------------------------------

static inline char* carve(char*& p, size_t bytes) {
    char* r = p;
    p += (bytes + 255) & ~(size_t)255;
    return r;
}

extern "C" void kernel_launch(void* const* d_in, const int* in_sizes, int n_in,
                              void* d_out, int out_size, void* d_ws, size_t ws_size,
                              hipStream_t stream) {
    const float* X  = (const float*)d_in[0];
    const float* W1 = (const float*)d_in[1];
    const float* b1 = (const float*)d_in[2];
    const float* W2 = (const float*)d_in[3];
    const float* b2 = (const float*)d_in[4];
    const float* W3 = (const float*)d_in[5];
    const float* b3 = (const float*)d_in[6];
    const float* pa = (const float*)d_in[7];
    const int* ei   = (const int*)d_in[8];
    const int* src = ei;
    const int* dst = ei + EB;
    float* out = (float*)d_out;

    char* p = (char*)d_ws;
    int* bins    = (int*)carve(p, NB * sizeof(int));
    int* loc     = (int*)carve(p, NB * sizeof(int));
    int* blksum  = (int*)carve(p, 128 * sizeof(int));
    int* rs      = (int*)carve(p, (NB + 1) * sizeof(int));
    int* cursor  = (int*)carve(p, NB * sizeof(int));
    int2* edges  = (int2*)carve(p, EB * sizeof(int2));
    float* dinv  = (float*)carve(p, NB * sizeof(float));
    float* bufA  = (float*)carve(p, (size_t)2 * NB * 256 * sizeof(float));
    float* bufB  = (float*)carve(p, (size_t)2 * NB * 256 * sizeof(float));

    const int M = 2 * NB;  // fused batch rows, node-interleaved [node*2+b][F]

    // --- CSR build ---
    zero_kernel<<<SCAN_BLOCKS, 256, 0, stream>>>(bins, NB);
    hist_kernel<<<(EB + 255) / 256, 256, 0, stream>>>(dst, bins);
    scanA_kernel<<<SCAN_BLOCKS, 256, 0, stream>>>(bins, loc, blksum);
    scanB_kernel<<<1, 128, 0, stream>>>(blksum);
    scanC_kernel<<<SCAN_BLOCKS, 256, 0, stream>>>(bins, loc, blksum, rs, cursor, dinv);
    scatter_kernel<<<(EB + 255) / 256, 256, 0, stream>>>(src, dst, dinv, cursor, edges);

    const int aggGrid = (NB / NPB) * 8;  // 125 chunks x 8 slices = 1000 blocks

    // Layer 1: aggregate X (batch-split in) -> bufA interleaved; GEMM(+b1,+prelu).
    aggs_kernel<128, true, false, false, false><<<aggGrid, 256, 0, stream>>>(
        X, bufA, rs, edges, dinv, nullptr, nullptr);
    gemm_kernel<true, true><<<dim3((M + 127) / 128, H1D / 64), 256, 0, stream>>>(
        bufA, M, DIN, W1, H1D, b1, pa, bufB);

    // Layer 2: GEMM then aggregate (+b2,+prelu), interleaved -> interleaved.
    gemm_kernel<false, false><<<dim3((M + 127) / 128, H2D / 64), 256, 0, stream>>>(
        bufB, M, H1D, W2, H2D, nullptr, nullptr, bufA);
    aggs_kernel<256, false, false, true, true><<<aggGrid, 256, 0, stream>>>(
        bufA, bufB, rs, edges, dinv, b2, pa);

    // Layer 3: GEMM then aggregate (+b3, no prelu) -> batch-split output.
    gemm_kernel<false, false><<<dim3((M + 127) / 128, DOUTD / 64), 256, 0, stream>>>(
        bufB, M, H2D, W3, DOUTD, nullptr, nullptr, bufA);
    aggs_kernel<128, false, true, true, false><<<aggGrid, 256, 0, stream>>>(
        bufA, out, rs, edges, dinv, b3, nullptr);
}

// Round 6
// 492.125 us; speedup vs baseline: 1.1017x; 1.1017x over previous
//
#include <hip/hip_runtime.h>

#define NB 20000
#define EB 320000
#define DIN 128
#define H1D 256
#define H2D 256
#define DOUTD 128
#define SCAN_BLOCKS ((NB + 255) / 256)   // 79
#define NPB 80                           // nodes per agg block (20000 = 250*80)

// ---------------------------------------------------------------------------
// CSR build: histogram -> parallel 3-phase scan -> dinv -> counting-sort
// scatter into int2{src, w_bits} edge records sorted by dst.
// ---------------------------------------------------------------------------

__global__ void zero_kernel(int* __restrict__ p, int n) {
    int t = blockIdx.x * blockDim.x + threadIdx.x;
    if (t < n) p[t] = 0;
}

__global__ void hist_kernel(const int* __restrict__ dst, int* __restrict__ bins) {
    int t = blockIdx.x * blockDim.x + threadIdx.x;
    if (t < EB) atomicAdd(&bins[dst[t]], 1);
}

__global__ __launch_bounds__(256) void scanA_kernel(const int* __restrict__ bins,
                                                    int* __restrict__ loc,
                                                    int* __restrict__ blksum) {
    __shared__ int s[256];
    int t = threadIdx.x;
    int i = blockIdx.x * 256 + t;
    int v = (i < NB) ? bins[i] : 0;
    s[t] = v;
    __syncthreads();
    for (int off = 1; off < 256; off <<= 1) {
        int u = (t >= off) ? s[t - off] : 0;
        __syncthreads();
        s[t] += u;
        __syncthreads();
    }
    if (i < NB) loc[i] = s[t] - v;
    if (t == 255) blksum[blockIdx.x] = s[255];
}

__global__ __launch_bounds__(128) void scanB_kernel(int* __restrict__ blksum) {
    __shared__ int s[128];
    int t = threadIdx.x;
    int v = (t < SCAN_BLOCKS) ? blksum[t] : 0;
    s[t] = v;
    __syncthreads();
    for (int off = 1; off < 128; off <<= 1) {
        int u = (t >= off) ? s[t - off] : 0;
        __syncthreads();
        s[t] += u;
        __syncthreads();
    }
    if (t < SCAN_BLOCKS) blksum[t] = s[t] - v;
}

__global__ __launch_bounds__(256) void scanC_kernel(const int* __restrict__ bins,
                                                    const int* __restrict__ loc,
                                                    const int* __restrict__ blksum,
                                                    int* __restrict__ rs,
                                                    int* __restrict__ cursor,
                                                    float* __restrict__ dinv) {
    int i = blockIdx.x * 256 + threadIdx.x;
    if (i < NB) {
        int r = loc[i] + blksum[blockIdx.x];
        rs[i] = r;
        cursor[i] = r;
        dinv[i] = rsqrtf((float)bins[i] + 1.0f);  // deg = in-degree + 1 (self loop)
    }
    if (i == 0) rs[NB] = EB;
}

__global__ void scatter_kernel(const int* __restrict__ src, const int* __restrict__ dst,
                               const float* __restrict__ dinv,
                               int* __restrict__ cursor, int2* __restrict__ edges) {
    int t = blockIdx.x * blockDim.x + threadIdx.x;
    if (t < EB) {
        int d = dst[t], s = src[t];
        int p = atomicAdd(&cursor[d], 1);
        edges[p] = make_int2(s, __float_as_int(dinv[s] * dinv[d]));
    }
}

// ---------------------------------------------------------------------------
// XCD-sliced aggregation, wave-uniform edge walk (round-5 fix).
// Feature dim split into 8 slices; slice s handled only by blocks with
// blockIdx.x%8==s (round-robin -> XCD s). Per-XCD gather working set:
// 2.5 MB (F=128) / 5.1 MB (F=256) vs 4 MB L2 -> (mostly) L2-resident.
// Execution: ONE FLOAT PER LANE. An edge's slice payload = 2 batches x SLW
// floats = ROWF lanes; EPW = 64/ROWF edges are processed per wave-step
// (F=256: 1 edge by the full wave; F=128: 2 edges by the two 32-lane
// halves, combined once per node via shfl_xor). Edge-loop bounds are
// wave-uniform (readfirstlane) -> ZERO divergence; 2-deep unroll -> 4 edges
// in flight. NPB=80 -> 2000 blocks = ~31 waves/CU.
// ---------------------------------------------------------------------------

template <int F, bool SPLIT_IN, bool SPLIT_OUT, bool BIAS, bool PRELU>
__global__ __launch_bounds__(256) void aggs_kernel(
    const float* __restrict__ h, float* __restrict__ out,
    const int* __restrict__ rs, const int2* __restrict__ edges,
    const float* __restrict__ dinv, const float* __restrict__ bias,
    const float* __restrict__ pa) {
    constexpr int SLW = F / 8;        // floats per batch per slice: 16 / 32
    constexpr int ROWF = 2 * SLW;     // lanes per edge: 32 / 64
    constexpr int EPW = 64 / ROWF;    // edges per wave-step: 2 / 1
    constexpr int GSTRIDE = SPLIT_IN ? F : 2 * F;
    constexpr int OSTRIDE = SPLIT_OUT ? F : 2 * F;

    const int s = blockIdx.x & 7;
    const int chunk = blockIdx.x >> 3;
    const int wid = threadIdx.x >> 6;
    const int lane = threadIdx.x & 63;
    const int half = lane / ROWF;     // which edge in the step (0..EPW-1)
    const int li = lane % ROWF;
    const int b = li / SLW;           // batch
    const int c = li % SLW;           // float within slice
    const int foff = s * SLW + c;

    const float* gbase = h + (SPLIT_IN ? (size_t)b * NB * F : (size_t)b * F) + foff;
    float* obase = out + (SPLIT_OUT ? (size_t)b * NB * F : (size_t)b * F) + foff;
    const float pav = PRELU ? *pa : 0.0f;
    const float bval = BIAS ? bias[foff] : 0.0f;

    const int npw = NPB / 4;
    int n = chunk * NPB + wid * npw;
    for (int j = 0; j < npw; ++j, ++n) {
        int e0 = __builtin_amdgcn_readfirstlane(rs[n]);
        int e1 = __builtin_amdgcn_readfirstlane(rs[n + 1]);
        float acc0 = 0.0f, acc1 = 0.0f;
        int e = e0;
        for (; e + 2 * EPW <= e1; e += 2 * EPW) {
            int2 ed0 = edges[e + half];
            int2 ed1 = edges[e + EPW + half];
            float t0 = gbase[(size_t)ed0.x * GSTRIDE];
            float t1 = gbase[(size_t)ed1.x * GSTRIDE];
            acc0 = fmaf(t0, __int_as_float(ed0.y), acc0);
            acc1 = fmaf(t1, __int_as_float(ed1.y), acc1);
        }
        for (; e < e1; e += EPW) {
            int my_e = e + half;
            bool valid = (my_e < e1);
            int2 ed = edges[valid ? my_e : (e1 - 1)];
            float t = gbase[(size_t)ed.x * GSTRIDE];
            float w = valid ? __int_as_float(ed.y) : 0.0f;
            acc0 = fmaf(t, w, acc0);
        }
        float acc = acc0 + acc1;
        if (EPW == 2) acc += __shfl_xor(acc, 32, 64);
        float dv = dinv[n];
        float ts = gbase[(size_t)n * GSTRIDE];
        float r = fmaf(ts, dv * dv, acc);
        if (BIAS) r += bval;
        if (PRELU) r = (r >= 0.0f) ? r : pav * r;
        if (EPW == 1 || half == 0) obase[(size_t)n * OSTRIDE] = r;
    }
}

// ---------------------------------------------------------------------------
// FP32 GEMM: C[M,Nc] = A[M,K] @ W[K,Nc] (+bias) (+prelu).
// 128x64 tile, BK=16, 256 threads, 8x4 microtile. (unchanged)
// ---------------------------------------------------------------------------
template <bool BIAS, bool PRELU>
__global__ __launch_bounds__(256) void gemm_kernel(const float* __restrict__ A, int M, int K,
                                                   const float* __restrict__ W, int Nc,
                                                   const float* __restrict__ bias,
                                                   const float* __restrict__ pa,
                                                   float* __restrict__ C) {
    __shared__ alignas(16) float As[16][132];
    __shared__ alignas(16) float Bs[16][68];
    int t = threadIdx.x;
    int bm = blockIdx.x * 128;
    int bn = blockIdx.y * 64;
    int tx = t & 15, ty = t >> 4;
    int m0 = ty * 8, n0 = tx * 4;
    int ar = t >> 2, ac4 = (t & 3) * 4;
    int br = t >> 4, bc4 = (t & 15) * 4;

    float acc[8][4] = {};

    for (int k0 = 0; k0 < K; k0 += 16) {
        float4 a0 = make_float4(0.f, 0.f, 0.f, 0.f), a1 = a0;
        int r0 = bm + ar, r1 = bm + ar + 64;
        if (r0 < M) a0 = *(const float4*)&A[(size_t)r0 * K + k0 + ac4];
        if (r1 < M) a1 = *(const float4*)&A[(size_t)r1 * K + k0 + ac4];
        As[ac4 + 0][ar] = a0.x; As[ac4 + 1][ar] = a0.y;
        As[ac4 + 2][ar] = a0.z; As[ac4 + 3][ar] = a0.w;
        As[ac4 + 0][ar + 64] = a1.x; As[ac4 + 1][ar + 64] = a1.y;
        As[ac4 + 2][ar + 64] = a1.z; As[ac4 + 3][ar + 64] = a1.w;
        float4 bv = *(const float4*)&W[(size_t)(k0 + br) * Nc + bn + bc4];
        *(float4*)&Bs[br][bc4] = bv;
        __syncthreads();
#pragma unroll
        for (int k = 0; k < 16; ++k) {
            float4 av0 = *(const float4*)&As[k][m0];
            float4 av1 = *(const float4*)&As[k][m0 + 4];
            float4 bv4 = *(const float4*)&Bs[k][n0];
            float a_[8] = {av0.x, av0.y, av0.z, av0.w, av1.x, av1.y, av1.z, av1.w};
            float b_[4] = {bv4.x, bv4.y, bv4.z, bv4.w};
#pragma unroll
            for (int i = 0; i < 8; ++i)
#pragma unroll
                for (int j = 0; j < 4; ++j)
                    acc[i][j] = fmaf(a_[i], b_[j], acc[i][j]);
        }
        __syncthreads();
    }

    float pav = 0.0f;
    if (PRELU) pav = *pa;
#pragma unroll
    for (int i = 0; i < 8; ++i) {
        int row = bm + m0 + i;
        if (row < M) {
            float v[4];
#pragma unroll
            for (int j = 0; j < 4; ++j) {
                float x = acc[i][j];
                if (BIAS) x += bias[bn + n0 + j];
                if (PRELU) x = (x >= 0.0f) ? x : pav * x;
                v[j] = x;
            }
            *(float4*)&C[(size_t)row * Nc + bn + n0] = make_float4(v[0], v[1], v[2], v[3]);
        }
    }
}

// ---------------------------------------------------------------------------

static inline char* carve(char*& p, size_t bytes) {
    char* r = p;
    p += (bytes + 255) & ~(size_t)255;
    return r;
}

extern "C" void kernel_launch(void* const* d_in, const int* in_sizes, int n_in,
                              void* d_out, int out_size, void* d_ws, size_t ws_size,
                              hipStream_t stream) {
    const float* X  = (const float*)d_in[0];
    const float* W1 = (const float*)d_in[1];
    const float* b1 = (const float*)d_in[2];
    const float* W2 = (const float*)d_in[3];
    const float* b2 = (const float*)d_in[4];
    const float* W3 = (const float*)d_in[5];
    const float* b3 = (const float*)d_in[6];
    const float* pa = (const float*)d_in[7];
    const int* ei   = (const int*)d_in[8];
    const int* src = ei;
    const int* dst = ei + EB;
    float* out = (float*)d_out;

    char* p = (char*)d_ws;
    int* bins    = (int*)carve(p, NB * sizeof(int));
    int* loc     = (int*)carve(p, NB * sizeof(int));
    int* blksum  = (int*)carve(p, 128 * sizeof(int));
    int* rs      = (int*)carve(p, (NB + 1) * sizeof(int));
    int* cursor  = (int*)carve(p, NB * sizeof(int));
    int2* edges  = (int2*)carve(p, EB * sizeof(int2));
    float* dinv  = (float*)carve(p, NB * sizeof(float));
    float* bufA  = (float*)carve(p, (size_t)2 * NB * 256 * sizeof(float));
    float* bufB  = (float*)carve(p, (size_t)2 * NB * 256 * sizeof(float));

    const int M = 2 * NB;  // fused batch rows, node-interleaved [node*2+b][F]

    // --- CSR build ---
    zero_kernel<<<SCAN_BLOCKS, 256, 0, stream>>>(bins, NB);
    hist_kernel<<<(EB + 255) / 256, 256, 0, stream>>>(dst, bins);
    scanA_kernel<<<SCAN_BLOCKS, 256, 0, stream>>>(bins, loc, blksum);
    scanB_kernel<<<1, 128, 0, stream>>>(blksum);
    scanC_kernel<<<SCAN_BLOCKS, 256, 0, stream>>>(bins, loc, blksum, rs, cursor, dinv);
    scatter_kernel<<<(EB + 255) / 256, 256, 0, stream>>>(src, dst, dinv, cursor, edges);

    const int aggGrid = (NB / NPB) * 8;  // 250 chunks x 8 slices = 2000 blocks

    // Layer 1: aggregate X (batch-split in) -> bufA interleaved; GEMM(+b1,+prelu).
    aggs_kernel<128, true, false, false, false><<<aggGrid, 256, 0, stream>>>(
        X, bufA, rs, edges, dinv, nullptr, nullptr);
    gemm_kernel<true, true><<<dim3((M + 127) / 128, H1D / 64), 256, 0, stream>>>(
        bufA, M, DIN, W1, H1D, b1, pa, bufB);

    // Layer 2: GEMM then aggregate (+b2,+prelu), interleaved -> interleaved.
    gemm_kernel<false, false><<<dim3((M + 127) / 128, H2D / 64), 256, 0, stream>>>(
        bufB, M, H1D, W2, H2D, nullptr, nullptr, bufA);
    aggs_kernel<256, false, false, true, true><<<aggGrid, 256, 0, stream>>>(
        bufA, bufB, rs, edges, dinv, b2, pa);

    // Layer 3: GEMM then aggregate (+b3, no prelu) -> batch-split output.
    gemm_kernel<false, false><<<dim3((M + 127) / 128, DOUTD / 64), 256, 0, stream>>>(
        bufB, M, H2D, W3, DOUTD, nullptr, nullptr, bufA);
    aggs_kernel<128, false, true, true, false><<<aggGrid, 256, 0, stream>>>(
        bufA, out, rs, edges, dinv, b3, nullptr);
}

// Round 7
// 444.928 us; speedup vs baseline: 1.2186x; 1.1061x over previous
//
#include <hip/hip_runtime.h>

#define NB 20000
#define EB 320000
#define DIN 128
#define H1D 256
#define H2D 256
#define DOUTD 128
#define SCAN_BLOCKS ((NB + 255) / 256)   // 79

// ---------------------------------------------------------------------------
// CSR build: histogram -> parallel 3-phase scan -> dinv -> counting-sort
// scatter into int2{src, w_bits} edge records sorted by dst.
// ---------------------------------------------------------------------------

__global__ void zero_kernel(int* __restrict__ p, int n) {
    int t = blockIdx.x * blockDim.x + threadIdx.x;
    if (t < n) p[t] = 0;
}

__global__ void hist_kernel(const int* __restrict__ dst, int* __restrict__ bins) {
    int t = blockIdx.x * blockDim.x + threadIdx.x;
    if (t < EB) atomicAdd(&bins[dst[t]], 1);
}

__global__ __launch_bounds__(256) void scanA_kernel(const int* __restrict__ bins,
                                                    int* __restrict__ loc,
                                                    int* __restrict__ blksum) {
    __shared__ int s[256];
    int t = threadIdx.x;
    int i = blockIdx.x * 256 + t;
    int v = (i < NB) ? bins[i] : 0;
    s[t] = v;
    __syncthreads();
    for (int off = 1; off < 256; off <<= 1) {
        int u = (t >= off) ? s[t - off] : 0;
        __syncthreads();
        s[t] += u;
        __syncthreads();
    }
    if (i < NB) loc[i] = s[t] - v;
    if (t == 255) blksum[blockIdx.x] = s[255];
}

__global__ __launch_bounds__(128) void scanB_kernel(int* __restrict__ blksum) {
    __shared__ int s[128];
    int t = threadIdx.x;
    int v = (t < SCAN_BLOCKS) ? blksum[t] : 0;
    s[t] = v;
    __syncthreads();
    for (int off = 1; off < 128; off <<= 1) {
        int u = (t >= off) ? s[t - off] : 0;
        __syncthreads();
        s[t] += u;
        __syncthreads();
    }
    if (t < SCAN_BLOCKS) blksum[t] = s[t] - v;
}

__global__ __launch_bounds__(256) void scanC_kernel(const int* __restrict__ bins,
                                                    const int* __restrict__ loc,
                                                    const int* __restrict__ blksum,
                                                    int* __restrict__ rs,
                                                    int* __restrict__ cursor,
                                                    float* __restrict__ dinv) {
    int i = blockIdx.x * 256 + threadIdx.x;
    if (i < NB) {
        int r = loc[i] + blksum[blockIdx.x];
        rs[i] = r;
        cursor[i] = r;
        dinv[i] = rsqrtf((float)bins[i] + 1.0f);  // deg = in-degree + 1 (self loop)
    }
    if (i == 0) rs[NB] = EB;
}

__global__ void scatter_kernel(const int* __restrict__ src, const int* __restrict__ dst,
                               const float* __restrict__ dinv,
                               int* __restrict__ cursor, int2* __restrict__ edges) {
    int t = blockIdx.x * blockDim.x + threadIdx.x;
    if (t < EB) {
        int d = dst[t], s = src[t];
        int p = atomicAdd(&cursor[d], 1);
        edges[p] = make_int2(s, __float_as_int(dinv[s] * dinv[d]));
    }
}

// ---------------------------------------------------------------------------
// Per-batch aggregation body: one wave per node, lane holds F/64 floats,
// 4-edge unroll -> 4 independent gathers in flight. Wave-uniform bounds.
// ---------------------------------------------------------------------------

__device__ inline void vload(float (&d)[4], const float* p) {
    float4 t = *(const float4*)p; d[0] = t.x; d[1] = t.y; d[2] = t.z; d[3] = t.w;
}
__device__ inline void vload(float (&d)[2], const float* p) {
    float2 t = *(const float2*)p; d[0] = t.x; d[1] = t.y;
}
__device__ inline void vstore(float* p, const float (&d)[4]) {
    *(float4*)p = make_float4(d[0], d[1], d[2], d[3]);
}
__device__ inline void vstore(float* p, const float (&d)[2]) {
    *(float2*)p = make_float2(d[0], d[1]);
}

template <int F, bool BIAS, bool PRELU>
__device__ void agg_body(int ablk,
                         const float* __restrict__ h, float* __restrict__ out,
                         const int* __restrict__ rs, const int2* __restrict__ edges,
                         const float* __restrict__ dinv, const float* __restrict__ bias,
                         const float* __restrict__ pa) {
    constexpr int VEC = F / 64;
    int wid = threadIdx.x >> 6;
    int lane = threadIdx.x & 63;
    int node = ablk * 4 + wid;           // grids sized so node < NB always
    const float* hsrc = h + (size_t)lane * VEC;

    float acc0[VEC], acc1[VEC] = {}, acc2[VEC] = {}, acc3[VEC] = {};
    {
        float dv = dinv[node];
        float sw = dv * dv;
        float t[VEC];
        vload(t, hsrc + (size_t)node * F);
#pragma unroll
        for (int v = 0; v < VEC; ++v) acc0[v] = t[v] * sw;
    }
    int e0 = __builtin_amdgcn_readfirstlane(rs[node]);
    int e1 = __builtin_amdgcn_readfirstlane(rs[node + 1]);
    int e = e0;
    for (; e + 4 <= e1; e += 4) {
        int2 d0 = edges[e], d1 = edges[e + 1], d2 = edges[e + 2], d3 = edges[e + 3];
        float t0[VEC], t1[VEC], t2[VEC], t3[VEC];
        vload(t0, hsrc + (size_t)d0.x * F);
        vload(t1, hsrc + (size_t)d1.x * F);
        vload(t2, hsrc + (size_t)d2.x * F);
        vload(t3, hsrc + (size_t)d3.x * F);
        float w0 = __int_as_float(d0.y), w1 = __int_as_float(d1.y);
        float w2 = __int_as_float(d2.y), w3 = __int_as_float(d3.y);
#pragma unroll
        for (int v = 0; v < VEC; ++v) {
            acc0[v] = fmaf(t0[v], w0, acc0[v]);
            acc1[v] = fmaf(t1[v], w1, acc1[v]);
            acc2[v] = fmaf(t2[v], w2, acc2[v]);
            acc3[v] = fmaf(t3[v], w3, acc3[v]);
        }
    }
    for (; e < e1; ++e) {
        int2 d0 = edges[e];
        float t0[VEC];
        vload(t0, hsrc + (size_t)d0.x * F);
        float w0 = __int_as_float(d0.y);
#pragma unroll
        for (int v = 0; v < VEC; ++v) acc0[v] = fmaf(t0[v], w0, acc0[v]);
    }
#pragma unroll
    for (int v = 0; v < VEC; ++v) acc0[v] += (acc1[v] + acc2[v]) + acc3[v];
    if (BIAS) {
        float bv[VEC];
        vload(bv, bias + lane * VEC);
#pragma unroll
        for (int v = 0; v < VEC; ++v) acc0[v] += bv[v];
    }
    if (PRELU) {
        float a = *pa;
#pragma unroll
        for (int v = 0; v < VEC; ++v) acc0[v] = acc0[v] >= 0.0f ? acc0[v] : a * acc0[v];
    }
    vstore(out + (size_t)node * F + lane * VEC, acc0);
}

// ---------------------------------------------------------------------------
// FP32 GEMM body: C[M,Nc] = A[M,K] @ W[K,Nc] (+bias) (+prelu).
// 128x64 tile, BK=16, 256 threads, 8x4 microtile. 1D block id gx.
// ---------------------------------------------------------------------------
template <bool BIAS, bool PRELU>
__device__ void gemm_body(int gx, const float* __restrict__ A, int M, int K,
                          const float* __restrict__ W, int Nc,
                          const float* __restrict__ bias, const float* __restrict__ pa,
                          float* __restrict__ C, int mt) {
    __shared__ alignas(16) float As[16][132];
    __shared__ alignas(16) float Bs[16][68];
    int t = threadIdx.x;
    int bm = (gx % mt) * 128;
    int bn = (gx / mt) * 64;
    int tx = t & 15, ty = t >> 4;
    int m0 = ty * 8, n0 = tx * 4;
    int ar = t >> 2, ac4 = (t & 3) * 4;
    int br = t >> 4, bc4 = (t & 15) * 4;

    float acc[8][4] = {};

    for (int k0 = 0; k0 < K; k0 += 16) {
        float4 a0 = make_float4(0.f, 0.f, 0.f, 0.f), a1 = a0;
        int r0 = bm + ar, r1 = bm + ar + 64;
        if (r0 < M) a0 = *(const float4*)&A[(size_t)r0 * K + k0 + ac4];
        if (r1 < M) a1 = *(const float4*)&A[(size_t)r1 * K + k0 + ac4];
        As[ac4 + 0][ar] = a0.x; As[ac4 + 1][ar] = a0.y;
        As[ac4 + 2][ar] = a0.z; As[ac4 + 3][ar] = a0.w;
        As[ac4 + 0][ar + 64] = a1.x; As[ac4 + 1][ar + 64] = a1.y;
        As[ac4 + 2][ar + 64] = a1.z; As[ac4 + 3][ar + 64] = a1.w;
        float4 bv = *(const float4*)&W[(size_t)(k0 + br) * Nc + bn + bc4];
        *(float4*)&Bs[br][bc4] = bv;
        __syncthreads();
#pragma unroll
        for (int k = 0; k < 16; ++k) {
            float4 av0 = *(const float4*)&As[k][m0];
            float4 av1 = *(const float4*)&As[k][m0 + 4];
            float4 bv4 = *(const float4*)&Bs[k][n0];
            float a_[8] = {av0.x, av0.y, av0.z, av0.w, av1.x, av1.y, av1.z, av1.w};
            float b_[4] = {bv4.x, bv4.y, bv4.z, bv4.w};
#pragma unroll
            for (int i = 0; i < 8; ++i)
#pragma unroll
                for (int j = 0; j < 4; ++j)
                    acc[i][j] = fmaf(a_[i], b_[j], acc[i][j]);
        }
        __syncthreads();
    }

    float pav = 0.0f;
    if (PRELU) pav = *pa;
#pragma unroll
    for (int i = 0; i < 8; ++i) {
        int row = bm + m0 + i;
        if (row < M) {
            float v[4];
#pragma unroll
            for (int j = 0; j < 4; ++j) {
                float x = acc[i][j];
                if (BIAS) x += bias[bn + n0 + j];
                if (PRELU) x = (x >= 0.0f) ? x : pav * x;
                v[j] = x;
            }
            *(float4*)&C[(size_t)row * Nc + bn + n0] = make_float4(v[0], v[1], v[2], v[3]);
        }
    }
}

// ---------------------------------------------------------------------------
// Standalone wrappers + the fat (GEMM || AGG) kernel. In the fat kernel,
// blocks are Bresenham-interleaved between the two bodies so both kinds stay
// co-resident as the dispatch drains (block-uniform branch; no inter-block
// dependence; deterministic).
// ---------------------------------------------------------------------------

template <int F, bool BIAS, bool PRELU>
__global__ __launch_bounds__(256) void agg_kernel(
    const float* __restrict__ h, float* __restrict__ out,
    const int* __restrict__ rs, const int2* __restrict__ edges,
    const float* __restrict__ dinv, const float* __restrict__ bias,
    const float* __restrict__ pa) {
    agg_body<F, BIAS, PRELU>(blockIdx.x, h, out, rs, edges, dinv, bias, pa);
}

template <bool BIAS, bool PRELU>
__global__ __launch_bounds__(256) void gemm_kernel(
    const float* __restrict__ A, int M, int K, const float* __restrict__ W, int Nc,
    const float* __restrict__ bias, const float* __restrict__ pa,
    float* __restrict__ C, int mt) {
    gemm_body<BIAS, PRELU>(blockIdx.x, A, M, K, W, Nc, bias, pa, C, mt);
}

template <int AF, bool AB, bool AP, bool GB, bool GP>
__global__ __launch_bounds__(256) void fat_kernel(
    // gemm slot
    const float* __restrict__ A, int M, int K, const float* __restrict__ W, int Nc,
    const float* __restrict__ gbias, float* __restrict__ C, int mt, int ng,
    // agg slot
    const float* __restrict__ ah, float* __restrict__ aout,
    const int* __restrict__ rs, const int2* __restrict__ edges,
    const float* __restrict__ dinv, const float* __restrict__ abias,
    const float* __restrict__ pa, int total) {
    int bx = blockIdx.x;
    int p0 = (int)((long long)bx * ng / total);
    int p1 = (int)(((long long)bx + 1) * ng / total);
    if (p1 > p0) {
        gemm_body<GB, GP>(p0, A, M, K, W, Nc, gbias, pa, C, mt);
    } else {
        agg_body<AF, AB, AP>(bx - p1, ah, aout, rs, edges, dinv, abias, pa);
    }
}

// ---------------------------------------------------------------------------

static inline char* carve(char*& p, size_t bytes) {
    char* r = p;
    p += (bytes + 255) & ~(size_t)255;
    return r;
}

extern "C" void kernel_launch(void* const* d_in, const int* in_sizes, int n_in,
                              void* d_out, int out_size, void* d_ws, size_t ws_size,
                              hipStream_t stream) {
    const float* X  = (const float*)d_in[0];
    const float* W1 = (const float*)d_in[1];
    const float* b1 = (const float*)d_in[2];
    const float* W2 = (const float*)d_in[3];
    const float* b2 = (const float*)d_in[4];
    const float* W3 = (const float*)d_in[5];
    const float* b3 = (const float*)d_in[6];
    const float* pa = (const float*)d_in[7];
    const int* ei   = (const int*)d_in[8];
    const int* src = ei;
    const int* dst = ei + EB;
    float* out = (float*)d_out;

    char* p = (char*)d_ws;
    int* bins    = (int*)carve(p, NB * sizeof(int));
    int* loc     = (int*)carve(p, NB * sizeof(int));
    int* blksum  = (int*)carve(p, 128 * sizeof(int));
    int* rs      = (int*)carve(p, (NB + 1) * sizeof(int));
    int* cursor  = (int*)carve(p, NB * sizeof(int));
    int2* edges  = (int2*)carve(p, EB * sizeof(int2));
    float* dinv  = (float*)carve(p, NB * sizeof(float));
    // Per-batch ping-pong buffers (each 20000 x 256 f32)
    float* P0 = (float*)carve(p, (size_t)NB * 256 * sizeof(float));
    float* Q0 = (float*)carve(p, (size_t)NB * 256 * sizeof(float));
    float* P1 = (float*)carve(p, (size_t)NB * 256 * sizeof(float));
    float* Q1 = (float*)carve(p, (size_t)NB * 256 * sizeof(float));

    const float* X0 = X;
    const float* X1 = X + (size_t)NB * DIN;
    float* out0 = out;
    float* out1 = out + (size_t)NB * DOUTD;

    // --- CSR build ---
    zero_kernel<<<SCAN_BLOCKS, 256, 0, stream>>>(bins, NB);
    hist_kernel<<<(EB + 255) / 256, 256, 0, stream>>>(dst, bins);
    scanA_kernel<<<SCAN_BLOCKS, 256, 0, stream>>>(bins, loc, blksum);
    scanB_kernel<<<1, 128, 0, stream>>>(blksum);
    scanC_kernel<<<SCAN_BLOCKS, 256, 0, stream>>>(bins, loc, blksum, rs, cursor, dinv);
    scatter_kernel<<<(EB + 255) / 256, 256, 0, stream>>>(src, dst, dinv, cursor, edges);

    const int AGG_BLK = NB / 4;             // 5000
    const int MT = (NB + 127) / 128;        // 157
    const int NG_256 = MT * (256 / 64);     // 628
    const int NG_128 = MT * (128 / 64);     // 314

    // Per-batch chain: A1 -> G1 -> G2 -> A2 -> G3 -> A3, staggered by 1 stage.

    // D1: A1(b0): X0 --agg--> P0 [F=128]
    agg_kernel<128, false, false><<<AGG_BLK, 256, 0, stream>>>(
        X0, P0, rs, edges, dinv, nullptr, nullptr);

    // D2: G1(b0): P0 @ W1 (+b1,prelu) -> Q0   ||   A1(b1): X1 -> P1
    fat_kernel<128, false, false, true, true><<<NG_256 + AGG_BLK, 256, 0, stream>>>(
        P0, NB, DIN, W1, H1D, b1, Q0, MT, NG_256,
        X1, P1, rs, edges, dinv, nullptr, pa, NG_256 + AGG_BLK);

    // D3: G2(b0): Q0 @ W2 -> P0   ;   G1(b1): P1 @ W1 (+b1,prelu) -> Q1
    gemm_kernel<false, false><<<NG_256, 256, 0, stream>>>(
        Q0, NB, H1D, W2, H2D, nullptr, nullptr, P0, MT);
    gemm_kernel<true, true><<<NG_256, 256, 0, stream>>>(
        P1, NB, DIN, W1, H1D, b1, pa, Q1, MT);

    // D4: G2(b1): Q1 @ W2 -> P1   ||   A2(b0): P0 --agg(+b2,prelu)--> Q0 [F=256]
    fat_kernel<256, true, true, false, false><<<NG_256 + AGG_BLK, 256, 0, stream>>>(
        Q1, NB, H1D, W2, H2D, nullptr, P1, MT, NG_256,
        P0, Q0, rs, edges, dinv, b2, pa, NG_256 + AGG_BLK);

    // D5: G3(b0): Q0 @ W3 -> P0   ||   A2(b1): P1 --agg(+b2,prelu)--> Q1 [F=256]
    fat_kernel<256, true, true, false, false><<<NG_128 + AGG_BLK, 256, 0, stream>>>(
        Q0, NB, H2D, W3, DOUTD, nullptr, P0, MT, NG_128,
        P1, Q1, rs, edges, dinv, b2, pa, NG_128 + AGG_BLK);

    // D6: G3(b1): Q1 @ W3 -> P1   ||   A3(b0): P0 --agg(+b3)--> out0 [F=128]
    fat_kernel<128, true, false, false, false><<<NG_128 + AGG_BLK, 256, 0, stream>>>(
        Q1, NB, H2D, W3, DOUTD, nullptr, P1, MT, NG_128,
        P0, out0, rs, edges, dinv, b3, nullptr, NG_128 + AGG_BLK);

    // D7: A3(b1): P1 --agg(+b3)--> out1 [F=128]
    agg_kernel<128, true, false><<<AGG_BLK, 256, 0, stream>>>(
        P1, out1, rs, edges, dinv, b3, nullptr);
}